// Round 2
// baseline (2486.006 us; speedup 1.0000x reference)
//
#include <hip/hip_runtime.h>

#define THREADS 256
#define MU_C  0.1f
#define EPS_C 0.01f

__device__ __forceinline__ float fast_tanh(float x) {
    // tanh(x) = 1 - 2/(exp2(x*2*log2 e)+1); saturates correctly at +-inf
    float e = __builtin_amdgcn_exp2f(x * 2.88539008177792681472f);
    return 1.0f - 2.0f * __builtin_amdgcn_rcpf(e + 1.0f);
}

// static-index dot products (callers pass reg arrays; fully inlined/unrolled)
__device__ __forceinline__ float dot16(const float* __restrict__ w, const float* h) {
    float a0 = 0.f, a1 = 0.f, a2 = 0.f, a3 = 0.f;
#pragma unroll
    for (int k = 0; k < 16; k += 4) {
        a0 += w[k + 0] * h[k + 0];
        a1 += w[k + 1] * h[k + 1];
        a2 += w[k + 2] * h[k + 2];
        a3 += w[k + 3] * h[k + 3];
    }
    return (a0 + a1) + (a2 + a3);
}

__device__ __forceinline__ float dot64(const float* __restrict__ w, const float* h) {
    float a0 = 0.f, a1 = 0.f, a2 = 0.f, a3 = 0.f;
#pragma unroll
    for (int k = 0; k < 64; k += 4) {
        a0 += w[k + 0] * h[k + 0];
        a1 += w[k + 1] * h[k + 1];
        a2 += w[k + 2] * h[k + 2];
        a3 += w[k + 3] * h[k + 3];
    }
    return (a0 + a1) + (a2 + a3);
}

// hh[64] = tanh( b2 + W2 @ tanh(b1 + W1 @ cz) ), h1 materialized 16 at a time
__device__ __forceinline__ void mlp_hidden(const float* __restrict__ W1,
                                           const float* __restrict__ b1,
                                           const float* __restrict__ W2,
                                           const float* __restrict__ b2,
                                           const float* cz, float* hh) {
#pragma unroll
    for (int o = 0; o < 64; ++o) hh[o] = b2[o];
#pragma unroll 1
    for (int c = 0; c < 4; ++c) {
        float h1c[16];
#pragma unroll
        for (int kk = 0; kk < 16; ++kk)
            h1c[kk] = fast_tanh(b1[c * 16 + kk] + dot16(W1 + (c * 16 + kk) * 16, cz));
#pragma unroll
        for (int kk = 0; kk < 16; ++kk) {
            const float hv = h1c[kk];
            const float* __restrict__ w2c = W2 + c * 16 + kk;  // column, stride 64
#pragma unroll
            for (int o = 0; o < 64; ++o) hh[o] += w2c[o * 64] * hv;
        }
    }
#pragma unroll
    for (int o = 0; o < 64; ++o) hh[o] = fast_tanh(hh[o]);
}

__global__ __launch_bounds__(THREADS)
__attribute__((amdgpu_waves_per_eu(2, 2)))
void ph_shnd_kernel(const float* __restrict__ zg, const float* __restrict__ ug,
                    const float* __restrict__ Wh1, const float* __restrict__ bh1,
                    const float* __restrict__ Wh2,
                    const float* __restrict__ W1jr, const float* __restrict__ b1jr,
                    const float* __restrict__ W2jr, const float* __restrict__ b2jr,
                    const float* __restrict__ W3jr, const float* __restrict__ b3jr,
                    const float* __restrict__ W1b, const float* __restrict__ b1b,
                    const float* __restrict__ W2b, const float* __restrict__ b2b,
                    const float* __restrict__ W3b, const float* __restrict__ b3b,
                    float* __restrict__ out, int B)
{
    // one 33-word slice per thread: [0:16) = gH, [16:32) = q/Bu scratch
    // word addr = tid*33 + c -> bank (tid*33+c)%32 = (tid+c)%32 : conflict-free
    __shared__ float slds[THREADS * 33];

    const int tid = threadIdx.x;
    const int idx = blockIdx.x * THREADS + tid;
    if (idx >= B) return;
    float* __restrict__ S = slds + tid * 33;

    float cz[16];
    {
        const float4* zp = reinterpret_cast<const float4*>(zg + (size_t)idx * 16);
        float4 a0 = zp[0], a1 = zp[1], a2 = zp[2], a3 = zp[3];
        cz[0]=a0.x; cz[1]=a0.y; cz[2]=a0.z; cz[3]=a0.w;
        cz[4]=a1.x; cz[5]=a1.y; cz[6]=a1.z; cz[7]=a1.w;
        cz[8]=a2.x; cz[9]=a2.y; cz[10]=a2.z; cz[11]=a2.w;
        cz[12]=a3.x; cz[13]=a3.y; cz[14]=a3.z; cz[15]=a3.w;
    }

#pragma unroll 1
    for (int pass = 0; pass < 2; ++pass) {
        float dz[16];

        // ================= Hamiltonian gradient =================
        {
            float fv[16];
#pragma unroll
            for (int i = 0; i < 16; ++i) fv[i] = MU_C * cz[i];
#pragma unroll 1
            for (int k = 0; k < 128; ++k) {
                float t = fast_tanh(bh1[k] + dot16(Wh1 + k * 16, cz));
#pragma unroll
                for (int i = 0; i < 16; ++i) fv[i] += Wh2[i * 128 + k] * t;
            }
            float gH[16];
#pragma unroll
            for (int i = 0; i < 16; ++i) gH[i] = MU_C * fv[i];
#pragma unroll 1
            for (int k = 0; k < 128; ++k) {
                float t = fast_tanh(bh1[k] + dot16(Wh1 + k * 16, cz));
                float v0 = 0.f, v1 = 0.f, v2 = 0.f, v3 = 0.f;
#pragma unroll
                for (int i = 0; i < 16; i += 4) {
                    v0 += Wh2[(i + 0) * 128 + k] * fv[i + 0];
                    v1 += Wh2[(i + 1) * 128 + k] * fv[i + 1];
                    v2 += Wh2[(i + 2) * 128 + k] * fv[i + 2];
                    v3 += Wh2[(i + 3) * 128 + k] * fv[i + 3];
                }
                float s = (1.0f - t * t) * ((v0 + v1) + (v2 + v3));
#pragma unroll
                for (int j = 0; j < 16; ++j) gH[j] += s * Wh1[k * 16 + j];
            }
            // gH -> LDS slice; init dz = -eps*gH; gH/fv regs die here
#pragma unroll
            for (int i = 0; i < 16; ++i) { S[i] = gH[i]; dz[i] = -EPS_C * gH[i]; }
        }

        // ================= JR net hiddens (hh = h2) =================
        float hh[64];
        mlp_hidden(W1jr, b1jr, W2jr, b2jr, cz, hh);

        // ================= Jm contraction: dz += Jm gH - Jm^T gH =================
#pragma unroll
        for (int j = 0; j < 16; ++j) S[16 + j] = 0.f;
#pragma unroll
        for (int i = 0; i < 16; ++i) {
            const float gHi = S[i];
            float pacc = 0.f;
#pragma unroll 1
            for (int j = 0; j < 16; ++j) {
                const int c = i * 16 + j;
                float val = b3jr[c] + dot64(W3jr + c * 64, hh);
                pacc += val * S[j];            // (Jm gH)_i
                S[16 + j] += val * gHi;        // (Jm^T gH)_j
            }
            dz[i] += pacc;
        }
#pragma unroll
        for (int j = 0; j < 16; ++j) dz[j] -= S[16 + j];

        // ================= R contraction: dz -= Rf (Rf^T gH), single pass =======
#pragma unroll 1
        for (int j = 0; j < 16; ++j) {
            float col[16];
#pragma unroll
            for (int i = 0; i < 16; ++i) {
                const int c = 256 + i * 16 + j;
                col[i] = b3jr[c] + dot64(W3jr + c * 64, hh);
            }
            float r0 = 0.f, r1 = 0.f, r2 = 0.f, r3 = 0.f;
#pragma unroll
            for (int i = 0; i < 16; i += 4) {
                r0 += col[i + 0] * S[i + 0];
                r1 += col[i + 1] * S[i + 1];
                r2 += col[i + 2] * S[i + 2];
                r3 += col[i + 3] * S[i + 3];
            }
            const float rfv = (r0 + r1) + (r2 + r3);   // (Rf^T gH)_j
#pragma unroll
            for (int i = 0; i < 16; ++i) dz[i] -= col[i] * rfv;
        }

        // ================= B net hiddens (hh = g2, reuse regs) =================
        mlp_hidden(W1b, b1b, W2b, b2b, cz, hh);

        // ================= B layer 3: Bu and y =================
        float uv[8];
        {
            const float4* up = reinterpret_cast<const float4*>(ug + (size_t)idx * 8);
            float4 u0 = up[0], u1 = up[1];
            uv[0]=u0.x; uv[1]=u0.y; uv[2]=u0.z; uv[3]=u0.w;
            uv[4]=u1.x; uv[5]=u1.y; uv[6]=u1.z; uv[7]=u1.w;
        }
        float yv[8];
#pragma unroll
        for (int m = 0; m < 8; ++m) yv[m] = 0.f;
#pragma unroll 1
        for (int d = 0; d < 16; ++d) {
            float row[8];
#pragma unroll
            for (int m = 0; m < 8; ++m) {
                const int c = d * 8 + m;
                row[m] = b3b[c] + dot64(W3b + c * 64, hh);
            }
            float bu = 0.f;
#pragma unroll
            for (int m = 0; m < 8; ++m) bu += row[m] * uv[m];
            S[16 + d] = bu;                     // scratch reused as Bu
            const float gHd = S[d];
#pragma unroll
            for (int m = 0; m < 8; ++m) yv[m] += row[m] * gHd;
        }
#pragma unroll
        for (int i = 0; i < 16; ++i) dz[i] += S[16 + i];

        // ================= pass epilogue =================
        float4* op = reinterpret_cast<float4*>(out + (size_t)idx * 16);
        if (pass == 0) {
#pragma unroll
            for (int i = 0; i < 16; ++i) cz[i] += dz[i];    // z1 = z0 + dz1
            // out = z0 + 0.5*dz1 = cz - 0.5*dz
#pragma unroll
            for (int q = 0; q < 4; ++q) {
                float4 o;
                o.x = cz[q*4+0] - 0.5f * dz[q*4+0];
                o.y = cz[q*4+1] - 0.5f * dz[q*4+1];
                o.z = cz[q*4+2] - 0.5f * dz[q*4+2];
                o.w = cz[q*4+3] - 0.5f * dz[q*4+3];
                op[q] = o;
            }
        } else {
            // out += 0.5*dz2
#pragma unroll
            for (int q = 0; q < 4; ++q) {
                float4 o = op[q];
                o.x += 0.5f * dz[q*4+0];
                o.y += 0.5f * dz[q*4+1];
                o.z += 0.5f * dz[q*4+2];
                o.w += 0.5f * dz[q*4+3];
                op[q] = o;
            }
            float4* yp = reinterpret_cast<float4*>(out + (size_t)B * 16 + (size_t)idx * 8);
            float4 y0, y1;
            y0.x = yv[0]; y0.y = yv[1]; y0.z = yv[2]; y0.w = yv[3];
            y1.x = yv[4]; y1.y = yv[5]; y1.z = yv[6]; y1.w = yv[7];
            yp[0] = y0;
            yp[1] = y1;
        }
    }
}

extern "C" void kernel_launch(void* const* d_in, const int* in_sizes, int n_in,
                              void* d_out, int out_size, void* d_ws, size_t ws_size,
                              hipStream_t stream) {
    const float* zg   = (const float*)d_in[0];
    const float* ug   = (const float*)d_in[1];
    const float* Wh1  = (const float*)d_in[2];
    const float* bh1  = (const float*)d_in[3];
    const float* Wh2  = (const float*)d_in[4];
    const float* W1jr = (const float*)d_in[5];
    const float* b1jr = (const float*)d_in[6];
    const float* W2jr = (const float*)d_in[7];
    const float* b2jr = (const float*)d_in[8];
    const float* W3jr = (const float*)d_in[9];
    const float* b3jr = (const float*)d_in[10];
    const float* W1b  = (const float*)d_in[11];
    const float* b1b  = (const float*)d_in[12];
    const float* W2b  = (const float*)d_in[13];
    const float* b2b  = (const float*)d_in[14];
    const float* W3b  = (const float*)d_in[15];
    const float* b3b  = (const float*)d_in[16];

    const int B = in_sizes[0] / 16;
    const int grid = (B + THREADS - 1) / THREADS;

    hipLaunchKernelGGL(ph_shnd_kernel, dim3(grid), dim3(THREADS), 0, stream,
                       zg, ug, Wh1, bh1, Wh2,
                       W1jr, b1jr, W2jr, b2jr, W3jr, b3jr,
                       W1b, b1b, W2b, b2b, W3b, b3b,
                       (float*)d_out, B);
}

// Round 3
// 518.430 us; speedup vs baseline: 4.7953x; 4.7953x over previous
//
#include <hip/hip_runtime.h>

#define THREADS 256
#define MU_C  0.1f
#define EPS_C 0.01f

typedef short bf16x8 __attribute__((ext_vector_type(8)));
typedef float f32x4  __attribute__((ext_vector_type(4)));

#define MFMA(a, b, c) __builtin_amdgcn_mfma_f32_16x16x32_bf16((a), (b), (c), 0, 0, 0)

__device__ __forceinline__ float ftanh(float x) {
    float e = __builtin_amdgcn_exp2f(x * 2.88539008177792681472f);
    return 1.0f - 2.0f * __builtin_amdgcn_rcpf(e + 1.0f);
}
// f32 -> bf16 round-to-nearest-ish (unbiased enough for 2% tol)
__device__ __forceinline__ short bfrn(float f) {
    unsigned u = __float_as_uint(f);
    return (short)((u + 0x8000u) >> 16);
}
__device__ __forceinline__ float bf2f(short s) {
    return __uint_as_float(((unsigned)(unsigned short)s) << 16);
}
// sum over the 16 lanes of a lane-group (masks 1,2,4,8)
__device__ __forceinline__ float rsum16(float v) {
    v += __shfl_xor(v, 1);
    v += __shfl_xor(v, 2);
    v += __shfl_xor(v, 4);
    v += __shfl_xor(v, 8);
    return v;
}

__device__ __forceinline__ bf16x8 pack8(float f0, float f1, float f2, float f3,
                                        float f4, float f5, float f6, float f7) {
    bf16x8 r;
    r[0] = bfrn(f0); r[1] = bfrn(f1); r[2] = bfrn(f2); r[3] = bfrn(f3);
    r[4] = bfrn(f4); r[5] = bfrn(f5); r[6] = bfrn(f6); r[7] = bfrn(f7);
    return r;
}

// B-fragment from global f32 weight matrix W[N][K] (row-major), output cols n0..n0+15.
// lane l supplies B[k=(l>>4)*8+j][col=n0+(l&15)] = W[n0+(l&15)][k0+(l>>4)*8+j]
__device__ __forceinline__ bf16x8 gblB(const float* __restrict__ W, int n0, int K, int k0, int lane) {
    const float* p = W + (size_t)(n0 + (lane & 15)) * K + k0 + (lane >> 4) * 8;
    float4 a = *reinterpret_cast<const float4*>(p);
    float4 b = *reinterpret_cast<const float4*>(p + 4);
    return pack8(a.x, a.y, a.z, a.w, b.x, b.y, b.z, b.w);
}
// K=16 variant (zero-padded to K=32): upper two lane-groups supply zeros.
__device__ __forceinline__ bf16x8 gblB16(const float* __restrict__ W, int n0, int lane) {
    int g = lane >> 4;
    if (g >= 2) {
        bf16x8 z = {0, 0, 0, 0, 0, 0, 0, 0};
        return z;
    }
    const float* p = W + (size_t)(n0 + (lane & 15)) * 16 + g * 8;
    float4 a = *reinterpret_cast<const float4*>(p);
    float4 b = *reinterpret_cast<const float4*>(p + 4);
    return pack8(a.x, a.y, a.z, a.w, b.x, b.y, b.z, b.w);
}
// A-fragment from LDS bf16 tile [16 rows][strideS shorts]:
// lane l reads A[row=l&15][k0 + (l>>4)*8 .. +7]
__device__ __forceinline__ bf16x8 ldsA(const short* base, int strideS, int lane, int k0) {
    return *reinterpret_cast<const bf16x8*>(base + (lane & 15) * strideS + k0 + (lane >> 4) * 8);
}

// per-wave LDS slice; all row strides are odd multiples of 16B (<=2-way bank alias, free)
struct __align__(16) WaveLds {
    short zt [16 * 40];    // z  bf16, K=32-padded (k>=16 zero), stride 80B
    short fvt[16 * 40];    // fv bf16, K=32-padded
    short t1 [16 * 136];   // t1 / s bf16, stride 272B (K=128)
    short h1t[16 * 72];    // h1/g1 bf16, stride 144B (K=64)
    short h2t[16 * 72];    // h2/g2 bf16
    float gHf[16 * 17];    // gH f32 (broadcast reads in contractions)
    float uf [16 * 9];     // u f32
};
struct __align__(16) BlockLds {
    WaveLds w[4];
    short wh2f[128 * 40];  // Wh2^T (for step3), K=32-padded
    short wh1t[16 * 136];  // Wh1^T (for step4)
    float bias[1024];      // bh1|b1jr|b2jr|b3jr|b1b|b2b|b3b @ 0|128|192|256|768|832|896
};

__global__ __launch_bounds__(THREADS)
void ph_mfma_kernel(const float* __restrict__ zg, const float* __restrict__ ug,
                    const float* __restrict__ Wh1, const float* __restrict__ bh1,
                    const float* __restrict__ Wh2,
                    const float* __restrict__ W1jr, const float* __restrict__ b1jr,
                    const float* __restrict__ W2jr, const float* __restrict__ b2jr,
                    const float* __restrict__ W3jr, const float* __restrict__ b3jr,
                    const float* __restrict__ W1b, const float* __restrict__ b1b,
                    const float* __restrict__ W2b, const float* __restrict__ b2b,
                    const float* __restrict__ W3b, const float* __restrict__ b3b,
                    float* __restrict__ out, int B)
{
    __shared__ BlockLds L;
    const int tid  = threadIdx.x;
    const int lane = tid & 63;
    const int wid  = tid >> 6;
    const int j2   = lane & 15;
    const int g    = lane >> 4;
    const int rowbase = blockIdx.x * 64 + wid * 16;
    if (rowbase >= B) return;

    // ================= block prologue =================
    for (int i = tid; i < 1024; i += THREADS) {
        float v;
        if      (i < 128) v = bh1[i];
        else if (i < 192) v = b1jr[i - 128];
        else if (i < 256) v = b2jr[i - 192];
        else if (i < 768) v = b3jr[i - 256];
        else if (i < 832) v = b1b[i - 768];
        else if (i < 896) v = b2b[i - 832];
        else              v = b3b[i - 896];
        L.bias[i] = v;
    }
    for (int i = tid; i < 128 * 40; i += THREADS) {      // Wh2f[n][k] = Wh2[k][n], pad 0
        int n = i / 40, k = i - n * 40;
        L.wh2f[i] = (k < 16) ? bfrn(Wh2[k * 128 + n]) : (short)0;
    }
    for (int i = tid; i < 16 * 136; i += THREADS) {      // Wh1T[n][k] = Wh1[k][n]
        int n = i / 136, k = i - n * 136;
        L.wh1t[i] = (k < 128) ? bfrn(Wh1[k * 16 + n]) : (short)0;
    }

    // ================= per-wave prologue =================
    WaveLds& Wv = L.w[wid];
    // zero only the K-pad region (shorts 16..39 = words 8..19 per row) of zt/fvt
    for (int i = lane; i < 16 * 12; i += 64) {
        int r = i / 12, w = i - r * 12;
        reinterpret_cast<unsigned*>(Wv.zt )[r * 20 + 8 + w] = 0;
        reinterpret_cast<unsigned*>(Wv.fvt)[r * 20 + 8 + w] = 0;
    }
    for (int i = lane; i < 128; i += 64) {               // u tile
        int r = i >> 3, m = i & 7;
        Wv.uf[r * 9 + m] = ug[(size_t)(rowbase + r) * 8 + m];
    }
    float zReg[4];                                        // z at this lane's C positions
#pragma unroll
    for (int reg = 0; reg < 4; ++reg) {
        int r = g * 4 + reg;
        float zv = zg[(size_t)(rowbase + r) * 16 + j2];
        zReg[reg] = zv;
        Wv.zt[r * 40 + j2] = bfrn(zv);
    }
    __syncthreads();

    // ================= two Heun passes =================
#pragma unroll 1
    for (int pass = 0; pass < 2; ++pass) {
        bf16x8 aZ = ldsA(Wv.zt, 40, lane, 0);

        // ---- step1: t1 = tanh(z @ Wh1^T + bh1)  [16x128, K=16] ----
#pragma unroll 2
        for (int nt = 0; nt < 8; ++nt) {
            f32x4 acc = {0.f, 0.f, 0.f, 0.f};
            acc = MFMA(aZ, gblB16(Wh1, nt * 16, lane), acc);
            float bb = L.bias[nt * 16 + j2];
#pragma unroll
            for (int reg = 0; reg < 4; ++reg)
                Wv.t1[(g * 4 + reg) * 136 + nt * 16 + j2] = bfrn(ftanh(acc[reg] + bb));
        }
        // ---- step2: fv = mu*z + t1 @ Wh2^T  [16x16, K=128] ----
        float fvReg[4];
        {
            f32x4 acc = {0.f, 0.f, 0.f, 0.f};
#pragma unroll
            for (int kt = 0; kt < 4; ++kt)
                acc = MFMA(ldsA(Wv.t1, 136, lane, kt * 32), gblB(Wh2, 0, 128, kt * 32, lane), acc);
#pragma unroll
            for (int reg = 0; reg < 4; ++reg) {
                float fv = acc[reg] + MU_C * zReg[reg];
                fvReg[reg] = fv;
                Wv.fvt[(g * 4 + reg) * 40 + j2] = bfrn(fv);
            }
        }
        // ---- step3: s = (1-t1^2) * (fv @ Wh2), in-place into t1  [16x128, K=16] ----
        bf16x8 aF = ldsA(Wv.fvt, 40, lane, 0);
#pragma unroll 2
        for (int nt = 0; nt < 8; ++nt) {
            f32x4 acc = {0.f, 0.f, 0.f, 0.f};
            acc = MFMA(aF, ldsA(L.wh2f + nt * 16 * 40, 40, lane, 0), acc);
#pragma unroll
            for (int reg = 0; reg < 4; ++reg) {
                int addr = (g * 4 + reg) * 136 + nt * 16 + j2;
                float t = bf2f(Wv.t1[addr]);
                Wv.t1[addr] = bfrn((1.f - t * t) * acc[reg]);
            }
        }
        // ---- step4: gH = mu*fv + s @ Wh1  [16x16, K=128] ----
        float gHj[4], dzAcc[4];
        {
            f32x4 acc = {0.f, 0.f, 0.f, 0.f};
#pragma unroll
            for (int kt = 0; kt < 4; ++kt)
                acc = MFMA(ldsA(Wv.t1, 136, lane, kt * 32), ldsA(L.wh1t, 136, lane, kt * 32), acc);
#pragma unroll
            for (int reg = 0; reg < 4; ++reg) {
                float gh = acc[reg] + MU_C * fvReg[reg];
                gHj[reg] = gh;                       // gH[r][j2] lane-local
                Wv.gHf[(g * 4 + reg) * 17 + j2] = gh;
                dzAcc[reg] = -EPS_C * gh;            // dz[r][i=j2] accumulator
            }
        }
        // ---- step5: h1 = tanh(z @ W1jr^T + b1jr)  [16x64, K=16] ----
#pragma unroll 2
        for (int nt = 0; nt < 4; ++nt) {
            f32x4 acc = {0.f, 0.f, 0.f, 0.f};
            acc = MFMA(aZ, gblB16(W1jr, nt * 16, lane), acc);
            float bb = L.bias[128 + nt * 16 + j2];
#pragma unroll
            for (int reg = 0; reg < 4; ++reg)
                Wv.h1t[(g * 4 + reg) * 72 + nt * 16 + j2] = bfrn(ftanh(acc[reg] + bb));
        }
        // ---- step6: h2 = tanh(h1 @ W2jr^T + b2jr)  [16x64, K=64] ----
        {
            bf16x8 a0 = ldsA(Wv.h1t, 72, lane, 0);
            bf16x8 a1 = ldsA(Wv.h1t, 72, lane, 32);
#pragma unroll 2
            for (int nt = 0; nt < 4; ++nt) {
                f32x4 acc = {0.f, 0.f, 0.f, 0.f};
                acc = MFMA(a0, gblB(W2jr, nt * 16, 64, 0,  lane), acc);
                acc = MFMA(a1, gblB(W2jr, nt * 16, 64, 32, lane), acc);
                float bb = L.bias[192 + nt * 16 + j2];
#pragma unroll
                for (int reg = 0; reg < 4; ++reg)
                    Wv.h2t[(g * 4 + reg) * 72 + nt * 16 + j2] = bfrn(ftanh(acc[reg] + bb));
            }
        }
        // ---- step7: JR layer-3 slabs fused with (J-R)gH contraction ----
        bf16x8 aH0 = ldsA(Wv.h2t, 72, lane, 0);
        bf16x8 aH1 = ldsA(Wv.h2t, 72, lane, 32);
        float qAcc[4]  = {0.f, 0.f, 0.f, 0.f};
        float rfvAcc[4] = {0.f, 0.f, 0.f, 0.f};
        // Jm slabs: slab n = row i=n of Jm, cols j=0..15
#pragma unroll 2
        for (int n = 0; n < 16; ++n) {
            f32x4 acc = {0.f, 0.f, 0.f, 0.f};
            acc = MFMA(aH0, gblB(W3jr, n * 16, 64, 0,  lane), acc);
            acc = MFMA(aH1, gblB(W3jr, n * 16, 64, 32, lane), acc);
            float bb = L.bias[256 + n * 16 + j2];
#pragma unroll
            for (int reg = 0; reg < 4; ++reg) {
                float val = acc[reg] + bb;               // Jm[r-elem][n][j2]
                float p = rsum16(val * gHj[reg]);        // (Jm gH)_n
                if (j2 == n) dzAcc[reg] += p;
                qAcc[reg] += val * Wv.gHf[(g * 4 + reg) * 17 + n];  // (Jm^T gH)_j2
            }
        }
        // Rf pass A: rfv_j = sum_i Rf[i][j] gH[i]
#pragma unroll 2
        for (int n = 0; n < 16; ++n) {
            f32x4 acc = {0.f, 0.f, 0.f, 0.f};
            acc = MFMA(aH0, gblB(W3jr, 256 + n * 16, 64, 0,  lane), acc);
            acc = MFMA(aH1, gblB(W3jr, 256 + n * 16, 64, 32, lane), acc);
            float bb = L.bias[512 + n * 16 + j2];
#pragma unroll
            for (int reg = 0; reg < 4; ++reg)
                rfvAcc[reg] += (acc[reg] + bb) * Wv.gHf[(g * 4 + reg) * 17 + n];
        }
        // Rf pass B: dz_i -= sum_j Rf[i][j] rfv_j  (recompute Rf slabs)
#pragma unroll 2
        for (int n = 0; n < 16; ++n) {
            f32x4 acc = {0.f, 0.f, 0.f, 0.f};
            acc = MFMA(aH0, gblB(W3jr, 256 + n * 16, 64, 0,  lane), acc);
            acc = MFMA(aH1, gblB(W3jr, 256 + n * 16, 64, 32, lane), acc);
            float bb = L.bias[512 + n * 16 + j2];
#pragma unroll
            for (int reg = 0; reg < 4; ++reg) {
                float racc = rsum16((acc[reg] + bb) * rfvAcc[reg]);
                if (j2 == n) dzAcc[reg] -= racc;
            }
        }
#pragma unroll
        for (int reg = 0; reg < 4; ++reg) dzAcc[reg] -= qAcc[reg];

        // ---- step8: g1,g2 (B-net hiddens, reuse h1t/h2t) ----
#pragma unroll 2
        for (int nt = 0; nt < 4; ++nt) {
            f32x4 acc = {0.f, 0.f, 0.f, 0.f};
            acc = MFMA(aZ, gblB16(W1b, nt * 16, lane), acc);
            float bb = L.bias[768 + nt * 16 + j2];
#pragma unroll
            for (int reg = 0; reg < 4; ++reg)
                Wv.h1t[(g * 4 + reg) * 72 + nt * 16 + j2] = bfrn(ftanh(acc[reg] + bb));
        }
        {
            bf16x8 a0 = ldsA(Wv.h1t, 72, lane, 0);
            bf16x8 a1 = ldsA(Wv.h1t, 72, lane, 32);
#pragma unroll 2
            for (int nt = 0; nt < 4; ++nt) {
                f32x4 acc = {0.f, 0.f, 0.f, 0.f};
                acc = MFMA(a0, gblB(W2b, nt * 16, 64, 0,  lane), acc);
                acc = MFMA(a1, gblB(W2b, nt * 16, 64, 32, lane), acc);
                float bb = L.bias[832 + nt * 16 + j2];
#pragma unroll
                for (int reg = 0; reg < 4; ++reg)
                    Wv.h2t[(g * 4 + reg) * 72 + nt * 16 + j2] = bfrn(ftanh(acc[reg] + bb));
            }
        }
        // ---- step9: Bmat slabs fused with Bu and y ----
        float yAcc[4] = {0.f, 0.f, 0.f, 0.f};
        {
            bf16x8 a0 = ldsA(Wv.h2t, 72, lane, 0);
            bf16x8 a1 = ldsA(Wv.h2t, 72, lane, 32);
            float uv[4];
#pragma unroll
            for (int reg = 0; reg < 4; ++reg) uv[reg] = Wv.uf[(g * 4 + reg) * 9 + (j2 & 7)];
#pragma unroll 2
            for (int n = 0; n < 8; ++n) {                 // slab n: d = 2n + (j2>>3), m = j2&7
                f32x4 acc = {0.f, 0.f, 0.f, 0.f};
                acc = MFMA(a0, gblB(W3b, n * 16, 64, 0,  lane), acc);
                acc = MFMA(a1, gblB(W3b, n * 16, 64, 32, lane), acc);
                float bb = L.bias[896 + n * 16 + j2];
#pragma unroll
                for (int reg = 0; reg < 4; ++reg) {
                    float val = acc[reg] + bb;
                    float s = val * uv[reg];              // half-reduce over m
                    s += __shfl_xor(s, 1);
                    s += __shfl_xor(s, 2);
                    s += __shfl_xor(s, 4);
                    float other = __shfl_xor(s, 8);
                    if (j2 == 2 * n)     dzAcc[reg] += (j2 < 8) ? s : other;
                    if (j2 == 2 * n + 1) dzAcc[reg] += (j2 < 8) ? other : s;
                    yAcc[reg] += val * Wv.gHf[(g * 4 + reg) * 17 + 2 * n + (j2 >> 3)];
                }
            }
        }
        // ---- pass epilogue ----
        if (pass == 0) {
#pragma unroll
            for (int reg = 0; reg < 4; ++reg) {
                int r = g * 4 + reg;
                float z1 = zReg[reg] + dzAcc[reg];       // DT = 1
                out[(size_t)(rowbase + r) * 16 + j2] = zReg[reg] + 0.5f * dzAcc[reg];
                zReg[reg] = z1;
                Wv.zt[r * 40 + j2] = bfrn(z1);
            }
        } else {
#pragma unroll
            for (int reg = 0; reg < 4; ++reg) {
                int r = g * 4 + reg;
                size_t o = (size_t)(rowbase + r) * 16 + j2;
                out[o] += 0.5f * dzAcc[reg];
                float yv = yAcc[reg] + __shfl_xor(yAcc[reg], 8);
                if (j2 < 8)
                    out[(size_t)B * 16 + (size_t)(rowbase + r) * 8 + j2] = yv;
            }
        }
    }
}

extern "C" void kernel_launch(void* const* d_in, const int* in_sizes, int n_in,
                              void* d_out, int out_size, void* d_ws, size_t ws_size,
                              hipStream_t stream) {
    const float* zg   = (const float*)d_in[0];
    const float* ug   = (const float*)d_in[1];
    const float* Wh1  = (const float*)d_in[2];
    const float* bh1  = (const float*)d_in[3];
    const float* Wh2  = (const float*)d_in[4];
    const float* W1jr = (const float*)d_in[5];
    const float* b1jr = (const float*)d_in[6];
    const float* W2jr = (const float*)d_in[7];
    const float* b2jr = (const float*)d_in[8];
    const float* W3jr = (const float*)d_in[9];
    const float* b3jr = (const float*)d_in[10];
    const float* W1b  = (const float*)d_in[11];
    const float* b1b  = (const float*)d_in[12];
    const float* W2b  = (const float*)d_in[13];
    const float* b2b  = (const float*)d_in[14];
    const float* W3b  = (const float*)d_in[15];
    const float* b3b  = (const float*)d_in[16];

    const int B = in_sizes[0] / 16;
    const int grid = (B + 63) / 64;   // 64 rows per block (4 waves x 16)

    hipLaunchKernelGGL(ph_mfma_kernel, dim3(grid), dim3(THREADS), 0, stream,
                       zg, ug, Wh1, bh1, Wh2,
                       W1jr, b1jr, W2jr, b2jr, W3jr, b3jr,
                       W1b, b1b, W2b, b2b, W3b, b3b,
                       (float*)d_out, B);
}

// Round 4
// 154.273 us; speedup vs baseline: 16.1143x; 3.3605x over previous
//
#include <hip/hip_runtime.h>

#define THREADS 256
#define MU_C  0.1f
#define EPS_C 0.01f

typedef short bf16x8 __attribute__((ext_vector_type(8)));
typedef float f32x4  __attribute__((ext_vector_type(4)));

#define MFMA(a, b, c) __builtin_amdgcn_mfma_f32_16x16x32_bf16((a), (b), (c), 0, 0, 0)

// ---- prepacked tile enumeration (1 tile = 64 lanes x 16B = 1 KB in d_ws) ----
#define T_WH1   0     // 8  : z @ Wh1^T       (K=16 pad32)
#define T_WH2   8     // 4  : t1 @ Wh2^T      (K=128)
#define T_WH2T  12    // 8  : fv @ Wh2        (K=16 pad32)
#define T_WH1T  20    // 4  : s  @ Wh1        (K=128)
#define T_W1JR  24    // 4  : z @ W1jr^T      (K=16 pad32)
#define T_W2JR  28    // 8  : h1 @ W2jr^T     (K=64)
#define T_JMN   36    // 32 : Jm normal slabs n=0..15, kt=0..1
#define T_JMT   68    // 32 : Jm transposed slabs t=0..15
#define T_RFN   100   // 32 : Rf normal
#define T_RFT   132   // 32 : Rf transposed
#define T_W1B   164   // 4  : z @ W1b^T       (K=16 pad32)
#define T_W2B   168   // 8  : g1 @ W2b^T      (K=64)
#define T_BMN   176   // 16 : Bmat normal n=0..7 (for y)
#define T_BMT   192   // 16 : Bmat transposed m=0..7 (for Bu)
#define NTILES  208

__device__ __forceinline__ float ftanh(float x) {
    float e = __builtin_amdgcn_exp2f(x * 2.88539008177792681472f);
    return 1.0f - 2.0f * __builtin_amdgcn_rcpf(e + 1.0f);
}
__device__ __forceinline__ short bfrn(float f) {
    unsigned u = __float_as_uint(f);
    return (short)((u + 0x8000u) >> 16);
}
__device__ __forceinline__ float bf2f(short s) {
    return __uint_as_float(((unsigned)(unsigned short)s) << 16);
}
__device__ __forceinline__ bf16x8 wsB(const short* __restrict__ ws, int tile, int lane) {
    return *reinterpret_cast<const bf16x8*>(ws + (size_t)((tile << 6) + lane) * 8);
}
// A-fragment from LDS bf16 tile [16 rows][strideS shorts]
__device__ __forceinline__ bf16x8 ldsA(const short* base, int strideS, int lane, int k0) {
    return *reinterpret_cast<const bf16x8*>(base + (lane & 15) * strideS + k0 + (lane >> 4) * 8);
}

// ==================== weight pre-pack kernel ====================
__global__ __launch_bounds__(256)
void pack_weights(const float* __restrict__ Wh1, const float* __restrict__ Wh2,
                  const float* __restrict__ W1jr, const float* __restrict__ W2jr,
                  const float* __restrict__ W3jr, const float* __restrict__ W1b,
                  const float* __restrict__ W2b, const float* __restrict__ W3b,
                  short* __restrict__ ws)
{
    const int id = blockIdx.x * 256 + threadIdx.x;
    if (id >= NTILES * 64) return;
    const int tile = id >> 6, lane = id & 63;
    const int j2 = lane & 15, g = lane >> 4;
    bf16x8 f;
#pragma unroll
    for (int jj = 0; jj < 8; ++jj) {
        const int k = g * 8 + jj;
        float x = 0.f;
        if (tile < T_WH2) {                                   // Wh1 [128][16], K16
            if (g < 2) x = Wh1[((tile - T_WH1) * 16 + j2) * 16 + k];
        } else if (tile < T_WH2T) {                           // Wh2^T frags: B[k][j2]=Wh2[j2][k]
            int kt = tile - T_WH2;
            x = Wh2[j2 * 128 + kt * 32 + k];
        } else if (tile < T_WH1T) {                           // Wh2 direction: B[k][j2]=Wh2[k][n0+j2]
            if (g < 2) x = Wh2[k * 128 + (tile - T_WH2T) * 16 + j2];
        } else if (tile < T_W1JR) {                           // Wh1 direction: B[k][j2]=Wh1[k][j2]
            int kt = tile - T_WH1T;
            x = Wh1[(kt * 32 + k) * 16 + j2];
        } else if (tile < T_W2JR) {
            if (g < 2) x = W1jr[((tile - T_W1JR) * 16 + j2) * 16 + k];
        } else if (tile < T_JMN) {
            int q = tile - T_W2JR; int nt = q >> 1, kt = q & 1;
            x = W2jr[(nt * 16 + j2) * 64 + kt * 32 + k];
        } else if (tile < T_JMT) {
            int q = tile - T_JMN; int n = q >> 1, kt = q & 1;
            x = W3jr[(n * 16 + j2) * 64 + kt * 32 + k];
        } else if (tile < T_RFN) {                            // Jm^T: row j2*16+t
            int q = tile - T_JMT; int t = q >> 1, kt = q & 1;
            x = W3jr[(j2 * 16 + t) * 64 + kt * 32 + k];
        } else if (tile < T_RFT) {
            int q = tile - T_RFN; int n = q >> 1, kt = q & 1;
            x = W3jr[(256 + n * 16 + j2) * 64 + kt * 32 + k];
        } else if (tile < T_W1B) {                            // Rf^T
            int q = tile - T_RFT; int t = q >> 1, kt = q & 1;
            x = W3jr[(256 + j2 * 16 + t) * 64 + kt * 32 + k];
        } else if (tile < T_W2B) {
            if (g < 2) x = W1b[((tile - T_W1B) * 16 + j2) * 16 + k];
        } else if (tile < T_BMN) {
            int q = tile - T_W2B; int nt = q >> 1, kt = q & 1;
            x = W2b[(nt * 16 + j2) * 64 + kt * 32 + k];
        } else if (tile < T_BMT) {
            int q = tile - T_BMN; int n = q >> 1, kt = q & 1;
            x = W3b[(n * 16 + j2) * 64 + kt * 32 + k];
        } else {                                              // Bmat^T: row j2*8+m
            int q = tile - T_BMT; int m = q >> 1, kt = q & 1;
            x = W3b[(j2 * 8 + m) * 64 + kt * 32 + k];
        }
        f[jj] = bfrn(x);
    }
    reinterpret_cast<bf16x8*>(ws)[id] = f;
}

// ==================== main kernel ====================
struct __align__(16) WaveLds {
    short zt [16 * 40];    // z  bf16, K=32-padded
    short fvt[16 * 40];    // fv bf16, K=32-padded
    short t1 [16 * 136];   // t1 / s bf16 (K=128)
    short h1t[16 * 72];    // h1/g1 bf16 (K=64)
    short h2t[16 * 72];    // h2/g2 bf16
    float gHf[16 * 17];    // gH f32 broadcast
    float rfv[16 * 17];    // Rf^T gH broadcast
    float uf [16 * 9];     // u f32 broadcast
};
struct __align__(16) BlockLds {
    WaveLds w[4];
    float bias[1664];
    // 0 bh1 |128 b1jr |192 b2jr |256 b3jr(512) |768 b1b |832 b2b |896 b3b(128)
    // 1024 bJmT[t*16+j] = b3jr[j*16+t]
    // 1280 bRfT[t*16+j] = b3jr[256+j*16+t]
    // 1536 bBmT[m*16+j] = b3b[j*8+m]
};

__global__ __launch_bounds__(THREADS)
void ph_mfma_kernel(const float* __restrict__ zg, const float* __restrict__ ug,
                    const float* __restrict__ bh1, const float* __restrict__ b1jr,
                    const float* __restrict__ b2jr, const float* __restrict__ b3jr,
                    const float* __restrict__ b1b, const float* __restrict__ b2b,
                    const float* __restrict__ b3b,
                    const short* __restrict__ ws,
                    float* __restrict__ out, int B)
{
    __shared__ BlockLds L;
    const int tid  = threadIdx.x;
    const int lane = tid & 63;
    const int wid  = tid >> 6;
    const int j2   = lane & 15;
    const int g    = lane >> 4;
    const int row  = g * 4;                 // base row of this lane's C-fragment
    const int rowbase = blockIdx.x * 64 + wid * 16;

    // ---- block prologue: biases (incl. transposed gathers) ----
    for (int i = tid; i < 1664; i += THREADS) {
        float v;
        if      (i < 128)  v = bh1[i];
        else if (i < 192)  v = b1jr[i - 128];
        else if (i < 256)  v = b2jr[i - 192];
        else if (i < 768)  v = b3jr[i - 256];
        else if (i < 832)  v = b1b[i - 768];
        else if (i < 896)  v = b2b[i - 832];
        else if (i < 1024) v = b3b[i - 896];
        else if (i < 1280) { int t = (i - 1024) >> 4, j = (i - 1024) & 15; v = b3jr[j * 16 + t]; }
        else if (i < 1536) { int t = (i - 1280) >> 4, j = (i - 1280) & 15; v = b3jr[256 + j * 16 + t]; }
        else               { int m = (i - 1536) >> 4, j = (i - 1536) & 15; v = b3b[j * 8 + m]; }
        L.bias[i] = v;
    }

    // ---- per-wave prologue ----
    WaveLds& Wv = L.w[wid];
    for (int i = lane; i < 16 * 12; i += 64) {     // zero K-pad of zt/fvt
        int r = i / 12, w = i - r * 12;
        reinterpret_cast<unsigned*>(Wv.zt )[r * 20 + 8 + w] = 0;
        reinterpret_cast<unsigned*>(Wv.fvt)[r * 20 + 8 + w] = 0;
    }
    for (int i = lane; i < 128; i += 64) {
        int r = i >> 3, m = i & 7;
        Wv.uf[r * 9 + m] = ug[(size_t)(rowbase + r) * 8 + m];
    }
    float zReg[4];
#pragma unroll
    for (int reg = 0; reg < 4; ++reg) {
        float zv = zg[(size_t)(rowbase + row + reg) * 16 + j2];
        zReg[reg] = zv;
        Wv.zt[(row + reg) * 40 + j2] = bfrn(zv);
    }
    __syncthreads();

#pragma unroll 1
    for (int pass = 0; pass < 2; ++pass) {
        bf16x8 aZ = ldsA(Wv.zt, 40, lane, 0);

        // ---- step1: t1 = tanh(z @ Wh1^T + bh1) ----
#pragma unroll 2
        for (int nt = 0; nt < 8; ++nt) {
            f32x4 acc = {0.f, 0.f, 0.f, 0.f};
            acc = MFMA(aZ, wsB(ws, T_WH1 + nt, lane), acc);
            float bb = L.bias[nt * 16 + j2];
#pragma unroll
            for (int reg = 0; reg < 4; ++reg)
                Wv.t1[(row + reg) * 136 + nt * 16 + j2] = bfrn(ftanh(acc[reg] + bb));
        }
        // ---- step2: fv = mu*z + t1 @ Wh2^T ----
        float fvReg[4];
        {
            f32x4 acc = {0.f, 0.f, 0.f, 0.f};
#pragma unroll
            for (int kt = 0; kt < 4; ++kt)
                acc = MFMA(ldsA(Wv.t1, 136, lane, kt * 32), wsB(ws, T_WH2 + kt, lane), acc);
#pragma unroll
            for (int reg = 0; reg < 4; ++reg) {
                float fv = acc[reg] + MU_C * zReg[reg];
                fvReg[reg] = fv;
                Wv.fvt[(row + reg) * 40 + j2] = bfrn(fv);
            }
        }
        // ---- step3: s = (1-t1^2)*(fv @ Wh2), in-place in t1 ----
        bf16x8 aF = ldsA(Wv.fvt, 40, lane, 0);
#pragma unroll 2
        for (int nt = 0; nt < 8; ++nt) {
            f32x4 acc = {0.f, 0.f, 0.f, 0.f};
            acc = MFMA(aF, wsB(ws, T_WH2T + nt, lane), acc);
#pragma unroll
            for (int reg = 0; reg < 4; ++reg) {
                int addr = (row + reg) * 136 + nt * 16 + j2;
                float t = bf2f(Wv.t1[addr]);
                Wv.t1[addr] = bfrn((1.f - t * t) * acc[reg]);
            }
        }
        // ---- step4: gH = mu*fv + s @ Wh1 ----
        float gHj[4], dzAcc[4];
        {
            f32x4 acc = {0.f, 0.f, 0.f, 0.f};
#pragma unroll
            for (int kt = 0; kt < 4; ++kt)
                acc = MFMA(ldsA(Wv.t1, 136, lane, kt * 32), wsB(ws, T_WH1T + kt, lane), acc);
#pragma unroll
            for (int reg = 0; reg < 4; ++reg) {
                float gh = acc[reg] + MU_C * fvReg[reg];
                gHj[reg] = gh;
                Wv.gHf[(row + reg) * 17 + j2] = gh;
                dzAcc[reg] = -EPS_C * gh;
            }
        }
        // ---- step5: h1 = tanh(z @ W1jr^T + b1jr) ----
#pragma unroll 2
        for (int nt = 0; nt < 4; ++nt) {
            f32x4 acc = {0.f, 0.f, 0.f, 0.f};
            acc = MFMA(aZ, wsB(ws, T_W1JR + nt, lane), acc);
            float bb = L.bias[128 + nt * 16 + j2];
#pragma unroll
            for (int reg = 0; reg < 4; ++reg)
                Wv.h1t[(row + reg) * 72 + nt * 16 + j2] = bfrn(ftanh(acc[reg] + bb));
        }
        // ---- step6: h2 = tanh(h1 @ W2jr^T + b2jr) ----
        {
            bf16x8 a0 = ldsA(Wv.h1t, 72, lane, 0);
            bf16x8 a1 = ldsA(Wv.h1t, 72, lane, 32);
#pragma unroll 2
            for (int nt = 0; nt < 4; ++nt) {
                f32x4 acc = {0.f, 0.f, 0.f, 0.f};
                acc = MFMA(a0, wsB(ws, T_W2JR + nt * 2 + 0, lane), acc);
                acc = MFMA(a1, wsB(ws, T_W2JR + nt * 2 + 1, lane), acc);
                float bb = L.bias[192 + nt * 16 + j2];
#pragma unroll
                for (int reg = 0; reg < 4; ++reg)
                    Wv.h2t[(row + reg) * 72 + nt * 16 + j2] = bfrn(ftanh(acc[reg] + bb));
            }
        }
        // ---- step7: (J - R) gH, all broadcast (no shfl) ----
        bf16x8 aH0 = ldsA(Wv.h2t, 72, lane, 0);
        bf16x8 aH1 = ldsA(Wv.h2t, 72, lane, 32);
        float qAcc[4] = {0.f, 0.f, 0.f, 0.f};
        // Jm normal: qAcc_j += Jm[n][j] * gH[n]    ((Jm^T gH)_j)
#pragma unroll 2
        for (int n = 0; n < 16; ++n) {
            f32x4 acc = {0.f, 0.f, 0.f, 0.f};
            acc = MFMA(aH0, wsB(ws, T_JMN + 2 * n + 0, lane), acc);
            acc = MFMA(aH1, wsB(ws, T_JMN + 2 * n + 1, lane), acc);
            float bb = L.bias[256 + n * 16 + j2];
#pragma unroll
            for (int reg = 0; reg < 4; ++reg)
                qAcc[reg] += (acc[reg] + bb) * Wv.gHf[(row + reg) * 17 + n];
        }
        // Jm transposed: dz_j += Jm[j][t] * gH[t]  ((Jm gH)_j)
#pragma unroll 2
        for (int t = 0; t < 16; ++t) {
            f32x4 acc = {0.f, 0.f, 0.f, 0.f};
            acc = MFMA(aH0, wsB(ws, T_JMT + 2 * t + 0, lane), acc);
            acc = MFMA(aH1, wsB(ws, T_JMT + 2 * t + 1, lane), acc);
            float bb = L.bias[1024 + t * 16 + j2];
#pragma unroll
            for (int reg = 0; reg < 4; ++reg)
                dzAcc[reg] += (acc[reg] + bb) * Wv.gHf[(row + reg) * 17 + t];
        }
#pragma unroll
        for (int reg = 0; reg < 4; ++reg) dzAcc[reg] -= qAcc[reg];
        // Rf normal: rfv_j = sum_n Rf[n][j] gH[n]
        {
            float rAcc[4] = {0.f, 0.f, 0.f, 0.f};
#pragma unroll 2
            for (int n = 0; n < 16; ++n) {
                f32x4 acc = {0.f, 0.f, 0.f, 0.f};
                acc = MFMA(aH0, wsB(ws, T_RFN + 2 * n + 0, lane), acc);
                acc = MFMA(aH1, wsB(ws, T_RFN + 2 * n + 1, lane), acc);
                float bb = L.bias[512 + n * 16 + j2];
#pragma unroll
                for (int reg = 0; reg < 4; ++reg)
                    rAcc[reg] += (acc[reg] + bb) * Wv.gHf[(row + reg) * 17 + n];
            }
#pragma unroll
            for (int reg = 0; reg < 4; ++reg)
                Wv.rfv[(row + reg) * 17 + j2] = rAcc[reg];
        }
        // Rf transposed: dz_j -= sum_t Rf[j][t] rfv[t]
#pragma unroll 2
        for (int t = 0; t < 16; ++t) {
            f32x4 acc = {0.f, 0.f, 0.f, 0.f};
            acc = MFMA(aH0, wsB(ws, T_RFT + 2 * t + 0, lane), acc);
            acc = MFMA(aH1, wsB(ws, T_RFT + 2 * t + 1, lane), acc);
            float bb = L.bias[1280 + t * 16 + j2];
#pragma unroll
            for (int reg = 0; reg < 4; ++reg)
                dzAcc[reg] -= (acc[reg] + bb) * Wv.rfv[(row + reg) * 17 + t];
        }
        // ---- step8: B-net hiddens (reuse h1t/h2t) ----
#pragma unroll 2
        for (int nt = 0; nt < 4; ++nt) {
            f32x4 acc = {0.f, 0.f, 0.f, 0.f};
            acc = MFMA(aZ, wsB(ws, T_W1B + nt, lane), acc);
            float bb = L.bias[768 + nt * 16 + j2];
#pragma unroll
            for (int reg = 0; reg < 4; ++reg)
                Wv.h1t[(row + reg) * 72 + nt * 16 + j2] = bfrn(ftanh(acc[reg] + bb));
        }
        {
            bf16x8 a0 = ldsA(Wv.h1t, 72, lane, 0);
            bf16x8 a1 = ldsA(Wv.h1t, 72, lane, 32);
#pragma unroll 2
            for (int nt = 0; nt < 4; ++nt) {
                f32x4 acc = {0.f, 0.f, 0.f, 0.f};
                acc = MFMA(a0, wsB(ws, T_W2B + nt * 2 + 0, lane), acc);
                acc = MFMA(a1, wsB(ws, T_W2B + nt * 2 + 1, lane), acc);
                float bb = L.bias[832 + nt * 16 + j2];
#pragma unroll
                for (int reg = 0; reg < 4; ++reg)
                    Wv.h2t[(row + reg) * 72 + nt * 16 + j2] = bfrn(ftanh(acc[reg] + bb));
            }
        }
        // ---- step9: y (normal slabs) and Bu (transposed slabs) ----
        float yAcc[4] = {0.f, 0.f, 0.f, 0.f};
        {
            bf16x8 a0 = ldsA(Wv.h2t, 72, lane, 0);
            bf16x8 a1 = ldsA(Wv.h2t, 72, lane, 32);
            // normal: cols j2 -> (d = 2n + (j2>>3), m = j2&7); y_m += B[d][m] gH[d]
#pragma unroll 2
            for (int n = 0; n < 8; ++n) {
                f32x4 acc = {0.f, 0.f, 0.f, 0.f};
                acc = MFMA(a0, wsB(ws, T_BMN + 2 * n + 0, lane), acc);
                acc = MFMA(a1, wsB(ws, T_BMN + 2 * n + 1, lane), acc);
                float bb = L.bias[896 + n * 16 + j2];
#pragma unroll
                for (int reg = 0; reg < 4; ++reg)
                    yAcc[reg] += (acc[reg] + bb) * Wv.gHf[(row + reg) * 17 + 2 * n + (j2 >> 3)];
            }
            // transposed: lane j2 = d; dz_d += B[d][m] * u[m]
#pragma unroll 2
            for (int m = 0; m < 8; ++m) {
                f32x4 acc = {0.f, 0.f, 0.f, 0.f};
                acc = MFMA(a0, wsB(ws, T_BMT + 2 * m + 0, lane), acc);
                acc = MFMA(a1, wsB(ws, T_BMT + 2 * m + 1, lane), acc);
                float bb = L.bias[1536 + m * 16 + j2];
#pragma unroll
                for (int reg = 0; reg < 4; ++reg)
                    dzAcc[reg] += (acc[reg] + bb) * Wv.uf[(row + reg) * 9 + m];
            }
        }
        // ---- pass epilogue ----
        if (pass == 0) {
#pragma unroll
            for (int reg = 0; reg < 4; ++reg) {
                int r = row + reg;
                float z1 = zReg[reg] + dzAcc[reg];
                out[(size_t)(rowbase + r) * 16 + j2] = zReg[reg] + 0.5f * dzAcc[reg];
                zReg[reg] = z1;
                Wv.zt[r * 40 + j2] = bfrn(z1);
            }
        } else {
#pragma unroll
            for (int reg = 0; reg < 4; ++reg) {
                int r = row + reg;
                out[(size_t)(rowbase + r) * 16 + j2] += 0.5f * dzAcc[reg];
                float yv = yAcc[reg] + __shfl_xor(yAcc[reg], 8);
                if (j2 < 8)
                    out[(size_t)B * 16 + (size_t)(rowbase + r) * 8 + j2] = yv;
            }
        }
    }
}

extern "C" void kernel_launch(void* const* d_in, const int* in_sizes, int n_in,
                              void* d_out, int out_size, void* d_ws, size_t ws_size,
                              hipStream_t stream) {
    const float* zg   = (const float*)d_in[0];
    const float* ug   = (const float*)d_in[1];
    const float* Wh1  = (const float*)d_in[2];
    const float* bh1  = (const float*)d_in[3];
    const float* Wh2  = (const float*)d_in[4];
    const float* W1jr = (const float*)d_in[5];
    const float* b1jr = (const float*)d_in[6];
    const float* W2jr = (const float*)d_in[7];
    const float* b2jr = (const float*)d_in[8];
    const float* W3jr = (const float*)d_in[9];
    const float* b3jr = (const float*)d_in[10];
    const float* W1b  = (const float*)d_in[11];
    const float* b1b  = (const float*)d_in[12];
    const float* W2b  = (const float*)d_in[13];
    const float* b2b  = (const float*)d_in[14];
    const float* W3b  = (const float*)d_in[15];
    const float* b3b  = (const float*)d_in[16];

    short* ws = (short*)d_ws;                       // needs NTILES KB = 208 KB
    const int B = in_sizes[0] / 16;

    hipLaunchKernelGGL(pack_weights, dim3((NTILES * 64 + 255) / 256), dim3(256), 0, stream,
                       Wh1, Wh2, W1jr, W2jr, W3jr, W1b, W2b, W3b, ws);

    const int grid = (B + 63) / 64;                 // 64 rows/block (4 waves x 16)
    hipLaunchKernelGGL(ph_mfma_kernel, dim3(grid), dim3(THREADS), 0, stream,
                       zg, ug, bh1, b1jr, b2jr, b3jr, b1b, b2b, b3b,
                       ws, (float*)d_out, B);
}